// Round 5
// baseline (187.831 us; speedup 1.0000x reference)
//
#include <hip/hip_runtime.h>

#define BIGV 1e4f

constexpr int RH = 8;   // output rows per thread
constexpr int TY = 4;   // waves per block (each wave = one y-strip)
constexpr int PX = 8;   // output px per thread in x

typedef float nf4 __attribute__((ext_vector_type(4)));   // native vec for nontemporal store

// Raw row: columns x-2 .. x+9 held as 2 aligned float4 + 2 halo float2.
// Unpacking is deferred to use-time so loads stay in flight (no early waitcnt).
struct Raw { float4 m0, m1; float2 L, R; };
struct Ero { float e[10]; };   // eroded columns x-1 .. x+8

__device__ __forceinline__ float min3f(float a, float b, float c) { return fminf(fminf(a, b), c); }
__device__ __forceinline__ float max3f(float a, float b, float c) { return fmaxf(fmaxf(a, b), c); }

// compile-time indexed access, i in [0,12) = img column x-2+i (folds under unroll)
__device__ __forceinline__ float rv(const Raw& r, int i) {
    switch (i) {
        case 0:  return r.L.x;  case 1:  return r.L.y;
        case 2:  return r.m0.x; case 3:  return r.m0.y;
        case 4:  return r.m0.z; case 5:  return r.m0.w;
        case 6:  return r.m1.x; case 7:  return r.m1.y;
        case 8:  return r.m1.z; case 9:  return r.m1.w;
        case 10: return r.R.x;  default: return r.R.y;
    }
}

__device__ __forceinline__ Raw load_raw(const float* __restrict__ img, int y, int x,
                                        int H, int W) {
    Raw r;
    if (y >= 0 && y < H) {                       // wave-uniform (y uniform per wave)
        const float* q = img + (size_t)y * W;
        r.m0 = *(const float4*)(q + x);
        r.m1 = *(const float4*)(q + x + 4);
        r.L = make_float2(BIGV, BIGV);
        r.R = make_float2(BIGV, BIGV);
        if (x > 0)      r.L = *(const float2*)(q + x - 2);
        if (x + PX < W) r.R = *(const float2*)(q + x + PX);
    } else {
        r.m0 = make_float4(BIGV, BIGV, BIGV, BIGV);
        r.m1 = r.m0;
        r.L = make_float2(BIGV, BIGV);
        r.R = r.L;
    }
    return r;
}

// ---- cross structuring element fast path: min/max over {C,N,S,W,E} ----
__device__ __forceinline__ Ero erode_cross(const Raw& a, const Raw& b, const Raw& c,
                                           int y, int H, int x, int W) {
    Ero e;
    if (y >= 0 && y < H) {                       // wave-uniform
#pragma unroll
        for (int j = 0; j < 10; ++j) {           // eroded column x-1+j
            float v = min3f(rv(a, j + 1), rv(b, j + 1), rv(c, j + 1));
            e.e[j] = min3f(v, rv(b, j), rv(b, j + 2));
        }
        if (x == 0)      e.e[0] = -BIGV;         // eroded col -1 -> dilation pad
        if (x + PX >= W) e.e[9] = -BIGV;         // eroded col W  -> dilation pad
    } else {
#pragma unroll
        for (int j = 0; j < 10; ++j) e.e[j] = -BIGV;
    }
    return e;
}

__device__ __forceinline__ void dilate_cross(const Ero& t, const Ero& m, const Ero& b,
                                             nf4& o0, nf4& o1) {
    float o[PX];
#pragma unroll
    for (int j = 0; j < PX; ++j)                 // out column x+j
        o[j] = max3f(max3f(t.e[j + 1], m.e[j + 1], b.e[j + 1]), m.e[j], m.e[j + 2]);
    o0 = (nf4){o[0], o[1], o[2], o[3]};
    o1 = (nf4){o[4], o[5], o[6], o[7]};
}

// ---- generic runtime-mask fallback (uniform branch; not taken in this bench) ----
__device__ __forceinline__ Ero erode_gen(const Raw& a, const Raw& b, const Raw& c,
                                         const bool* m, int y, int H, int x, int W) {
    Ero e;
    if (y >= 0 && y < H) {
#pragma unroll
        for (int j = 0; j < 10; ++j) {           // eroded column x-1+j
            float acc = BIGV;
#pragma unroll
            for (int k = 0; k < 9; ++k) {
                const int di = k / 3, dj = k % 3;
                const Raw& rr = (di == 0) ? a : ((di == 1) ? b : c);
                acc = fminf(acc, m[k] ? rv(rr, j + dj) : BIGV);
            }
            e.e[j] = acc;
        }
        if (x == 0)      e.e[0] = -BIGV;
        if (x + PX >= W) e.e[9] = -BIGV;
    } else {
#pragma unroll
        for (int j = 0; j < 10; ++j) e.e[j] = -BIGV;
    }
    return e;
}

__device__ __forceinline__ void dilate_gen(const Ero& t, const Ero& md, const Ero& b,
                                           const bool* m, nf4& o0, nf4& o1) {
    float o[PX];
#pragma unroll
    for (int j = 0; j < PX; ++j) {               // out column x+j
        float acc = -BIGV;
#pragma unroll
        for (int k = 0; k < 9; ++k) {
            const int di = k / 3, dj = k % 3;
            const Ero& ee = (di == 0) ? t : ((di == 1) ? md : b);
            acc = fmaxf(acc, m[k] ? ee.e[j + dj] : -BIGV);
        }
        o[j] = acc;
    }
    o0 = (nf4){o[0], o[1], o[2], o[3]};
    o1 = (nf4){o[4], o[5], o[6], o[7]};
}

template <bool CROSS>
__device__ __forceinline__ void run(const float* __restrict__ img, float* __restrict__ out,
                                    const bool* m, int x, int y0, int H, int W) {
    // prologue: img rows y0-2 .. y0+2, eroded rows y0-1, y0
    Raw r0 = load_raw(img, y0 - 2, x, H, W);
    Raw r1 = load_raw(img, y0 - 1, x, H, W);
    Raw r2 = load_raw(img, y0,     x, H, W);
    Raw r3 = load_raw(img, y0 + 1, x, H, W);
    Raw pf = load_raw(img, y0 + 2, x, H, W);     // row y0+2, consumed at i=0

    Ero E0 = CROSS ? erode_cross(r0, r1, r2, y0 - 1, H, x, W)
                   : erode_gen(r0, r1, r2, m, y0 - 1, H, x, W);
    Ero E1 = CROSS ? erode_cross(r1, r2, r3, y0, H, x, W)
                   : erode_gen(r1, r2, r3, m, y0, H, x, W);
    Raw A = r2, B = r3;                          // img rows y0+i, y0+i+1

#pragma unroll
    for (int i = 0; i < RH; ++i) {
        const int y = y0 + i;
        Raw nf = pf;
        if (i < RH - 1)                          // compile-time under unroll
            nf = load_raw(img, y + 3, x, H, W);  // prefetch next iteration's row
        Ero E2 = CROSS ? erode_cross(A, B, pf, y + 1, H, x, W)
                       : erode_gen(A, B, pf, m, y + 1, H, x, W);
        nf4 o0, o1;
        if (CROSS) dilate_cross(E0, E1, E2, o0, o1);
        else       dilate_gen(E0, E1, E2, m, o0, o1);
        float* po = out + (size_t)y * W + x;
        __builtin_nontemporal_store(o0, (nf4*)po);
        __builtin_nontemporal_store(o1, (nf4*)(po + 4));
        A = B; B = pf; pf = nf;
        E0 = E1; E1 = E2;
    }
}

__global__ __launch_bounds__(256) void opening_kernel(
    const float* __restrict__ img, const int* __restrict__ kern,
    float* __restrict__ out, int H, int W)
{
    const int lx = threadIdx.x & 63;             // lane -> x strip of 8 px
    const int ty = threadIdx.x >> 6;             // wave -> y strip (wave-uniform)
    const int x  = blockIdx.x * (64 * PX) + lx * PX;
    const int y0 = (blockIdx.y * TY + ty) * RH;
    const size_t pbase = (size_t)blockIdx.z * H * W;

    bool m[9];
#pragma unroll
    for (int k = 0; k < 9; ++k) m[k] = (kern[k] == 1);

    const bool cross = m[1] && m[3] && m[4] && m[5] && m[7] &&
                       !m[0] && !m[2] && !m[6] && !m[8];

    if (cross) run<true >(img + pbase, out + pbase, m, x, y0, H, W);
    else       run<false>(img + pbase, out + pbase, m, x, y0, H, W);
}

extern "C" void kernel_launch(void* const* d_in, const int* in_sizes, int n_in,
                              void* d_out, int out_size, void* d_ws, size_t ws_size,
                              hipStream_t stream) {
    const float* img  = (const float*)d_in[0];
    const int*   kern = (const int*)d_in[1];
    float*       out  = (float*)d_out;

    const int H = 1024, W = 1024;
    const int planes = in_sizes[0] / (H * W);    // B*C = 24

    dim3 block(256);
    dim3 grid(W / (64 * PX), H / (TY * RH), planes);  // (2, 32, 24) = 1536 blocks
    opening_kernel<<<grid, block, 0, stream>>>(img, kern, out, H, W);
}